// Round 1
// baseline (4922.352 us; speedup 1.0000x reference)
//
#include <hip/hip_runtime.h>

// LightGCN on MI355X (gfx950). Round 9.
// Theory this round: spmm is bound by L2-miss fill traffic (FETCH 305MB @ ~3.2TB/s
// accounts for the full 94.5us) — x (19.2MB bf16) is L3-resident, but random 128B
// row-gathers miss the 4MB/XCD L2 ~50%. Fix = column-locality scheduling:
//  * partB counting-sorts each row-bucket's edges by COLUMN bucket (512 cols),
//    staged in LDS and written back IN PLACE (tmp doubles as fin; no rowptr; edges
//    are int2 with full fp32 vals — 14-bit quantization removed).
//  * spmm: one block per row-bucket (RPB=293 rows, NBUCK=512 = 2 blocks/CU, one
//    round), LDS fp32 accumulator (stride 68 to spread banks by 4*rl), ds_add_f32
//    accumulation, edge-parallel (8 lanes x 16B per edge — no per-wave max-degree
//    divergence), unroll-4 for gather ILP. All ~64 resident blocks per XCD sweep
//    the cb-sorted edge stream in lockstep -> gathers hit L2; x fetched ~once/XCD.
// R7 lesson kept: NO nontemporal ops anywhere; windowed scatters rely on L2.

#define NUSERS 100000
#define NITEMS 50000
#define NTOT   150000
#define DIM    64
#define NNZ_E  4800000

#define RPB     293    // rows per bucket (fits 9 bits: 0..292)
#define NBUCK   512    // ceil(150000/293) -> exactly 2 blocks per CU in spmm
#define NCB     293    // column buckets of 512 cols (ceil(150000/512))
#define CHUNK_E 8192
#define NPART   ((NNZ_E + CHUNK_E - 1) / CHUNK_E) // 586
#define LST     68     // LDS accumulator row stride (floats); bank = (4*rl + 8s + j) & 31
#define BCAP    13000  // partB LDS staging cap (bucket mean 9375, sd ~97 -> +37 sigma)

__device__ __forceinline__ unsigned short benc(float f) {
    union { float f; unsigned u; } t; t.f = f;
    unsigned r = t.u + 0x7FFFu + ((t.u >> 16) & 1u);   // RNE
    return (unsigned short)(r >> 16);
}
__device__ __forceinline__ float blo(unsigned g) { return __uint_as_float(g << 16); }
__device__ __forceinline__ float bhi(unsigned g) { return __uint_as_float(g & 0xFFFF0000u); }

// ---- Pass 1: per-chunk LDS histogram -> TRANSPOSED count matrix cntmatT[b][p] ----
__global__ void __launch_bounds__(512)
partA1_kernel(const int* __restrict__ rows, int* __restrict__ cntmatT) {
    __shared__ int l[NBUCK];
    int p = blockIdx.x;
    int c0 = p * CHUNK_E;
    int c1 = c0 + CHUNK_E; if (c1 > NNZ_E) c1 = NNZ_E;
    for (int k = threadIdx.x; k < NBUCK; k += 512) l[k] = 0;
    __syncthreads();
    for (int e = c0 + threadIdx.x; e < c1; e += 512)
        atomicAdd(&l[rows[e] / RPB], 1);
    __syncthreads();
    for (int k = threadIdx.x; k < NBUCK; k += 512)
        cntmatT[(size_t)k * NPART + p] = l[k];
}

// ---- Per-bucket run-offset scan: block b scans cntmatT[b][0..NPART) ----
__global__ void __launch_bounds__(1024)
colscan1_kernel(const int* __restrict__ cntmatT, int* __restrict__ runoffT,
                int* __restrict__ colTotal) {
    __shared__ int t[1024];
    int b = blockIdx.x;
    int tid = threadIdx.x;
    int v = (tid < NPART) ? cntmatT[(size_t)b * NPART + tid] : 0;
    t[tid] = v;
    __syncthreads();
    for (int ofs = 1; ofs < 1024; ofs <<= 1) {
        int a = (tid >= ofs) ? t[tid - ofs] : 0;
        __syncthreads();
        t[tid] += a;
        __syncthreads();
    }
    if (tid < NPART) runoffT[(size_t)b * NPART + tid] = t[tid] - v;
    if (tid == NPART - 1) colTotal[b] = t[tid];
}

// ---- Exclusive scan of colTotal -> bptr[NBUCK+1] ----
__global__ void colscan2_kernel(const int* __restrict__ colTotal, int* __restrict__ bptr) {
    __shared__ int t[512];
    int tid = threadIdx.x;
    int v = (tid < NBUCK) ? colTotal[tid] : 0;
    t[tid] = v;
    __syncthreads();
    for (int ofs = 1; ofs < 512; ofs <<= 1) {
        int a = (tid >= ofs) ? t[tid - ofs] : 0;
        __syncthreads();
        t[tid] += a;
        __syncthreads();
    }
    if (tid < NBUCK) bptr[tid] = t[tid] - v;
    if (tid == 511) bptr[NBUCK] = t[511];
}

// ---- Pass 2: scatter into bucket runs (cursors precomputed; regular stores) ----
// tmp word: x = col | (row_local << 18), y = fp32 val bits (NO quantization).
__global__ void __launch_bounds__(512)
partA2_kernel(const int* __restrict__ rows, const int* __restrict__ cols,
              const float* __restrict__ vals, const int* __restrict__ runoffT,
              const int* __restrict__ bptr, int2* __restrict__ tmp) {
    __shared__ int cur[NBUCK];
    int p = blockIdx.x;
    int c0 = p * CHUNK_E;
    int c1 = c0 + CHUNK_E; if (c1 > NNZ_E) c1 = NNZ_E;
    for (int k = threadIdx.x; k < NBUCK; k += 512)
        cur[k] = bptr[k] + runoffT[(size_t)k * NPART + p];
    __syncthreads();
    for (int e = c0 + threadIdx.x; e < c1; e += 512) {
        int r = rows[e];
        int b = r / RPB;
        int rl = r - b * RPB;
        int q = atomicAdd(&cur[b], 1);
        tmp[q] = make_int2(cols[e] | (rl << 18), __float_as_int(vals[e]));
    }
}

// ---- Phase B: per-bucket counting sort by COLUMN bucket, IN PLACE via LDS stage ----
__global__ void __launch_bounds__(1024)
partB_kernel(const int* __restrict__ bptr, int2* __restrict__ tmp) {
    __shared__ int cnt[NCB];
    __shared__ int cur[NCB];
    __shared__ int2 buf[BCAP];
    int b = blockIdx.x;
    int bb0 = bptr[b];
    int nb = bptr[b + 1] - bb0;
    int tid = threadIdx.x;
    if (nb > BCAP) return;   // can't stage: leave bucket unsorted (correct, just slower)
    if (tid < NCB) cnt[tid] = 0;
    __syncthreads();
    for (int k = tid; k < nb; k += 1024) {
        int2 t = tmp[bb0 + k];
        buf[k] = t;
        atomicAdd(&cnt[(t.x & 0x3FFFF) >> 9], 1);
    }
    __syncthreads();
    int v = 0;
    if (tid < NCB) { v = cnt[tid]; cur[tid] = v; }
    __syncthreads();
    for (int ofs = 1; ofs < 512; ofs <<= 1) {
        int a = (tid < NCB && tid >= ofs) ? cur[tid - ofs] : 0;
        __syncthreads();
        if (tid < NCB) cur[tid] += a;
        __syncthreads();
    }
    if (tid < NCB) cur[tid] -= v;   // exclusive offsets
    __syncthreads();
    for (int k = tid; k < nb; k += 1024) {
        int2 t = buf[k];
        int q = atomicAdd(&cur[(t.x & 0x3FFFF) >> 9], 1);
        tmp[bb0 + q] = t;            // safe: whole bucket staged in LDS first
    }
}

// ---- x0h bf16-packed: uint j of row r = comps (2j, 2j+1) ----
__global__ void convert_kernel(const float2* __restrict__ user, const float2* __restrict__ item,
                               unsigned* __restrict__ xh2) {
    int i = blockIdx.x * blockDim.x + threadIdx.x;   // = row*32 + j
    if (i >= NTOT * 32) return;
    float2 v = (i < NUSERS * 32) ? user[i] : item[i - NUSERS * 32];
    xh2[i] = (unsigned)benc(v.x) | ((unsigned)benc(v.y) << 16);
}

// ---- SpMM: one block per row-bucket, LDS fp32 accumulator, cb-swept gathers ----
__global__ void __launch_bounds__(512, 4)
spmm2_kernel(const int* __restrict__ bptr, const int2* __restrict__ ed,
             const uint4* __restrict__ xin, uint4* __restrict__ yout,
             const float4* __restrict__ user, const float4* __restrict__ item,
             const uint4* __restrict__ y1, float4* __restrict__ out, int last) {
    __shared__ float acc[RPB * LST];   // 79,696 B -> exactly 2 blocks/CU
    int b = blockIdx.x;
    int tid = threadIdx.x;
    for (int k = tid; k < RPB * LST; k += 512) acc[k] = 0.f;
    __syncthreads();
    int e1 = bptr[b + 1];
    int s  = tid & 7;
    int s8 = s * 8;

#define EDGE_STEP(EE) do { \
        int2 t = ed[EE]; \
        int col = t.x & 0x3FFFF; \
        int rl  = t.x >> 18; \
        float v = __int_as_float(t.y); \
        uint4 g = xin[(size_t)col * 8 + s]; \
        int ab = rl * LST + s8; \
        atomicAdd(&acc[ab + 0], v * blo(g.x)); \
        atomicAdd(&acc[ab + 1], v * bhi(g.x)); \
        atomicAdd(&acc[ab + 2], v * blo(g.y)); \
        atomicAdd(&acc[ab + 3], v * bhi(g.y)); \
        atomicAdd(&acc[ab + 4], v * blo(g.z)); \
        atomicAdd(&acc[ab + 5], v * bhi(g.z)); \
        atomicAdd(&acc[ab + 6], v * blo(g.w)); \
        atomicAdd(&acc[ab + 7], v * bhi(g.w)); \
    } while (0)

    int e = bptr[b] + (tid >> 3);
    for (; e + 192 < e1; e += 256) {
        EDGE_STEP(e); EDGE_STEP(e + 64); EDGE_STEP(e + 128); EDGE_STEP(e + 192);
    }
    for (; e < e1; e += 64) EDGE_STEP(e);
#undef EDGE_STEP

    __syncthreads();

    int r0 = b * RPB;
    if (!last) {
        for (int rl = (tid >> 3); rl < RPB; rl += 64) {
            int r = r0 + rl;
            if (r >= NTOT) break;
            int ab = rl * LST + s8;
            uint4 o;
            o.x = (unsigned)benc(acc[ab + 0]) | ((unsigned)benc(acc[ab + 1]) << 16);
            o.y = (unsigned)benc(acc[ab + 2]) | ((unsigned)benc(acc[ab + 3]) << 16);
            o.z = (unsigned)benc(acc[ab + 4]) | ((unsigned)benc(acc[ab + 5]) << 16);
            o.w = (unsigned)benc(acc[ab + 6]) | ((unsigned)benc(acc[ab + 7]) << 16);
            yout[(size_t)r * 8 + s] = o;
        }
    } else {
        for (int rl = (tid >> 3); rl < RPB; rl += 64) {
            int r = r0 + rl;
            if (r >= NTOT) break;
            int ab = rl * LST + s8;
            size_t f4 = (size_t)r * 16 + 2 * s;   // float4 index of comps [8s, 8s+8)
            float4 x0a = (r < NUSERS) ? user[f4]     : item[f4     - (size_t)NUSERS * 16];
            float4 x0b = (r < NUSERS) ? user[f4 + 1] : item[f4 + 1 - (size_t)NUSERS * 16];
            uint4 u1 = y1[(size_t)r * 8 + s];
            uint4 u2 = xin[(size_t)r * 8 + s];   // layer-3 input IS y2
            float4 oa, ob;
            oa.x = 0.25f * (x0a.x + blo(u1.x) + blo(u2.x) + acc[ab + 0]);
            oa.y = 0.25f * (x0a.y + bhi(u1.x) + bhi(u2.x) + acc[ab + 1]);
            oa.z = 0.25f * (x0a.z + blo(u1.y) + blo(u2.y) + acc[ab + 2]);
            oa.w = 0.25f * (x0a.w + bhi(u1.y) + bhi(u2.y) + acc[ab + 3]);
            ob.x = 0.25f * (x0b.x + blo(u1.z) + blo(u2.z) + acc[ab + 4]);
            ob.y = 0.25f * (x0b.y + bhi(u1.z) + bhi(u2.z) + acc[ab + 5]);
            ob.z = 0.25f * (x0b.z + blo(u1.w) + blo(u2.w) + acc[ab + 6]);
            ob.w = 0.25f * (x0b.w + bhi(u1.w) + bhi(u2.w) + acc[ab + 7]);
            out[f4]     = oa;
            out[f4 + 1] = ob;
        }
    }
}

extern "C" void kernel_launch(void* const* d_in, const int* in_sizes, int n_in,
                              void* d_out, int out_size, void* d_ws, size_t ws_size,
                              hipStream_t stream) {
    const float* user = (const float*)d_in[0];
    const float* item = (const float*)d_in[1];
    const float* vals = (const float*)d_in[2];
    const int*   rows = (const int*)d_in[3];
    const int*   cols = (const int*)d_in[4];
    float* out = (float*)d_out;

    // ws layout (~79 MB): tmp 38.4M (in-place cb-sorted edges) | bufA 19.2M |
    // bufB 19.2M | cntmatT 1.2M | runoffT 1.2M | colTotal 2K | bptr 2K
    char* w = (char*)d_ws;
    int2*     tmp      = (int2*)w;     w += (size_t)NNZ_E * 8;
    unsigned* bufA     = (unsigned*)w; w += (size_t)NTOT * DIM * 2;   // x0h, later y2h
    unsigned* bufB     = (unsigned*)w; w += (size_t)NTOT * DIM * 2;   // y1h
    int*      cntmatT  = (int*)w;      w += (size_t)NBUCK * NPART * 4;
    int*      runoffT  = (int*)w;      w += (size_t)NBUCK * NPART * 4;
    int*      colTotal = (int*)w;      w += (size_t)NBUCK * 4;
    int*      bptr     = (int*)w;

    const int blk = 256;
    const int gConv = (NTOT * 32 + blk - 1) / blk;       // 18750

    // Deterministic two-pass counting partition (no global atomics, regular stores)
    partA1_kernel<<<NPART, 512, 0, stream>>>(rows, cntmatT);
    colscan1_kernel<<<NBUCK, 1024, 0, stream>>>(cntmatT, runoffT, colTotal);
    colscan2_kernel<<<1, 512, 0, stream>>>(colTotal, bptr);
    partA2_kernel<<<NPART, 512, 0, stream>>>(rows, cols, vals, runoffT, bptr, tmp);
    partB_kernel<<<NBUCK, 1024, 0, stream>>>(bptr, tmp);

    // Layer input in bf16
    convert_kernel<<<gConv, blk, 0, stream>>>((const float2*)user, (const float2*)item, bufA);

    // 3 propagation layers; layer 3 fuses the stage-mean into out
    spmm2_kernel<<<NBUCK, 512, 0, stream>>>(bptr, tmp, (const uint4*)bufA, (uint4*)bufB,
                                            (const float4*)user, (const float4*)item,
                                            (const uint4*)bufB, (float4*)out, 0); // y1=bufB
    spmm2_kernel<<<NBUCK, 512, 0, stream>>>(bptr, tmp, (const uint4*)bufB, (uint4*)bufA,
                                            (const float4*)user, (const float4*)item,
                                            (const uint4*)bufB, (float4*)out, 0); // y2=bufA
    spmm2_kernel<<<NBUCK, 512, 0, stream>>>(bptr, tmp, (const uint4*)bufA, (uint4*)bufA,
                                            (const float4*)user, (const float4*)item,
                                            (const uint4*)bufB, (float4*)out, 1); // fused mean
}

// Round 2
// 4907.047 us; speedup vs baseline: 1.0031x; 1.0031x over previous
//
#include <hip/hip_runtime.h>

// LightGCN on MI355X (gfx950). Round 10.
// R9 post-mortem: column-band locality WORKED (FETCH 305->214MB) but
// atomicAdd(__shared__ float*) lowered to a CAS loop (default fp-atomic
// semantics) -> ~0.6-1M LDS instrs/CU of dependent ds round-trips = 1560us/layer,
// VALUBusy 1.5%. Fix: native ds_add_f32 via inline asm (fire-and-forget, no
// return, drained by the pre-barrier waitcnt). Also LST 68->65: bank =
// (rl+8s+j)&31 instead of (4rl+8s+j)&31, which had collapsed even/odd rl groups
// onto two 4-bank sets (~8-way conflicts).
// Structure otherwise identical to R9: cb-sorted edges, 1 block/bucket,
// RPB=293/NBUCK=512 (2 blocks/CU), LDS fp32 accumulator, edge-parallel 8 lanes/edge.

#define NUSERS 100000
#define NITEMS 50000
#define NTOT   150000
#define DIM    64
#define NNZ_E  4800000

#define RPB     293    // rows per bucket (fits 9 bits via <<18 pack)
#define NBUCK   512    // exactly 2 blocks per CU in spmm
#define NCB     293    // column buckets of 512 cols
#define CHUNK_E 8192
#define NPART   ((NNZ_E + CHUNK_E - 1) / CHUNK_E) // 586
#define LST     65     // acc row stride (floats); bank = (rl + 8s + j) & 31
#define BCAP    13000  // partB LDS staging cap (bucket mean 9375, sd ~97)

__device__ __forceinline__ unsigned short benc(float f) {
    union { float f; unsigned u; } t; t.f = f;
    unsigned r = t.u + 0x7FFFu + ((t.u >> 16) & 1u);   // RNE
    return (unsigned short)(r >> 16);
}
__device__ __forceinline__ float blo(unsigned g) { return __uint_as_float(g << 16); }
__device__ __forceinline__ float bhi(unsigned g) { return __uint_as_float(g & 0xFFFF0000u); }

// Native LDS float atomic add. Generic->LDS pointer truncation is valid on gfx9:
// addrspacecast(3->flat) = {aperture_hi, lds_byte_offset}, low 32 bits ARE the
// ds offset. ds_add_f32 is fire-and-forget (no rtn); __syncthreads' lgkmcnt(0)
// drain makes results visible to the epilogue reads.
__device__ __forceinline__ void lds_fadd(float* p, float v) {
    unsigned a = (unsigned)(size_t)p;
    asm volatile("ds_add_f32 %0, %1" :: "v"(a), "v"(v) : "memory");
}

// ---- Pass 1: per-chunk LDS histogram -> TRANSPOSED count matrix cntmatT[b][p] ----
__global__ void __launch_bounds__(512)
partA1_kernel(const int* __restrict__ rows, int* __restrict__ cntmatT) {
    __shared__ int l[NBUCK];
    int p = blockIdx.x;
    int c0 = p * CHUNK_E;
    int c1 = c0 + CHUNK_E; if (c1 > NNZ_E) c1 = NNZ_E;
    for (int k = threadIdx.x; k < NBUCK; k += 512) l[k] = 0;
    __syncthreads();
    for (int e = c0 + threadIdx.x; e < c1; e += 512)
        atomicAdd(&l[rows[e] / RPB], 1);
    __syncthreads();
    for (int k = threadIdx.x; k < NBUCK; k += 512)
        cntmatT[(size_t)k * NPART + p] = l[k];
}

// ---- Per-bucket run-offset scan: block b scans cntmatT[b][0..NPART) ----
__global__ void __launch_bounds__(1024)
colscan1_kernel(const int* __restrict__ cntmatT, int* __restrict__ runoffT,
                int* __restrict__ colTotal) {
    __shared__ int t[1024];
    int b = blockIdx.x;
    int tid = threadIdx.x;
    int v = (tid < NPART) ? cntmatT[(size_t)b * NPART + tid] : 0;
    t[tid] = v;
    __syncthreads();
    for (int ofs = 1; ofs < 1024; ofs <<= 1) {
        int a = (tid >= ofs) ? t[tid - ofs] : 0;
        __syncthreads();
        t[tid] += a;
        __syncthreads();
    }
    if (tid < NPART) runoffT[(size_t)b * NPART + tid] = t[tid] - v;
    if (tid == NPART - 1) colTotal[b] = t[tid];
}

// ---- Exclusive scan of colTotal -> bptr[NBUCK+1] ----
__global__ void colscan2_kernel(const int* __restrict__ colTotal, int* __restrict__ bptr) {
    __shared__ int t[512];
    int tid = threadIdx.x;
    int v = (tid < NBUCK) ? colTotal[tid] : 0;
    t[tid] = v;
    __syncthreads();
    for (int ofs = 1; ofs < 512; ofs <<= 1) {
        int a = (tid >= ofs) ? t[tid - ofs] : 0;
        __syncthreads();
        t[tid] += a;
        __syncthreads();
    }
    if (tid < NBUCK) bptr[tid] = t[tid] - v;
    if (tid == 511) bptr[NBUCK] = t[511];
}

// ---- Pass 2: scatter into bucket runs (cursors precomputed; regular stores) ----
// tmp word: x = col | (row_local << 18), y = fp32 val bits.
__global__ void __launch_bounds__(512)
partA2_kernel(const int* __restrict__ rows, const int* __restrict__ cols,
              const float* __restrict__ vals, const int* __restrict__ runoffT,
              const int* __restrict__ bptr, int2* __restrict__ tmp) {
    __shared__ int cur[NBUCK];
    int p = blockIdx.x;
    int c0 = p * CHUNK_E;
    int c1 = c0 + CHUNK_E; if (c1 > NNZ_E) c1 = NNZ_E;
    for (int k = threadIdx.x; k < NBUCK; k += 512)
        cur[k] = bptr[k] + runoffT[(size_t)k * NPART + p];
    __syncthreads();
    for (int e = c0 + threadIdx.x; e < c1; e += 512) {
        int r = rows[e];
        int b = r / RPB;
        int rl = r - b * RPB;
        int q = atomicAdd(&cur[b], 1);
        tmp[q] = make_int2(cols[e] | (rl << 18), __float_as_int(vals[e]));
    }
}

// ---- Phase B: per-bucket counting sort by COLUMN bucket, IN PLACE via LDS stage ----
__global__ void __launch_bounds__(1024)
partB_kernel(const int* __restrict__ bptr, int2* __restrict__ tmp) {
    __shared__ int cnt[NCB];
    __shared__ int cur[NCB];
    __shared__ int2 buf[BCAP];
    int b = blockIdx.x;
    int bb0 = bptr[b];
    int nb = bptr[b + 1] - bb0;
    int tid = threadIdx.x;
    if (nb > BCAP) return;   // can't stage: leave bucket unsorted (correct, just slower)
    if (tid < NCB) cnt[tid] = 0;
    __syncthreads();
    for (int k = tid; k < nb; k += 1024) {
        int2 t = tmp[bb0 + k];
        buf[k] = t;
        atomicAdd(&cnt[(t.x & 0x3FFFF) >> 9], 1);
    }
    __syncthreads();
    int v = 0;
    if (tid < NCB) { v = cnt[tid]; cur[tid] = v; }
    __syncthreads();
    for (int ofs = 1; ofs < 512; ofs <<= 1) {
        int a = (tid < NCB && tid >= ofs) ? cur[tid - ofs] : 0;
        __syncthreads();
        if (tid < NCB) cur[tid] += a;
        __syncthreads();
    }
    if (tid < NCB) cur[tid] -= v;   // exclusive offsets
    __syncthreads();
    for (int k = tid; k < nb; k += 1024) {
        int2 t = buf[k];
        int q = atomicAdd(&cur[(t.x & 0x3FFFF) >> 9], 1);
        tmp[bb0 + q] = t;            // safe: whole bucket staged in LDS first
    }
}

// ---- x0h bf16-packed: uint j of row r = comps (2j, 2j+1) ----
__global__ void convert_kernel(const float2* __restrict__ user, const float2* __restrict__ item,
                               unsigned* __restrict__ xh2) {
    int i = blockIdx.x * blockDim.x + threadIdx.x;   // = row*32 + j
    if (i >= NTOT * 32) return;
    float2 v = (i < NUSERS * 32) ? user[i] : item[i - NUSERS * 32];
    xh2[i] = (unsigned)benc(v.x) | ((unsigned)benc(v.y) << 16);
}

// ---- SpMM: one block per row-bucket, LDS fp32 accumulator, cb-swept gathers ----
__global__ void __launch_bounds__(512, 4)
spmm2_kernel(const int* __restrict__ bptr, const int2* __restrict__ ed,
             const uint4* __restrict__ xin, uint4* __restrict__ yout,
             const float4* __restrict__ user, const float4* __restrict__ item,
             const uint4* __restrict__ y1, float4* __restrict__ out, int last) {
    __shared__ float acc[RPB * LST];   // 76,180 B -> 2 blocks/CU
    int b = blockIdx.x;
    int tid = threadIdx.x;
    for (int k = tid; k < RPB * LST; k += 512) acc[k] = 0.f;
    __syncthreads();
    int e1 = bptr[b + 1];
    int s  = tid & 7;
    int s8 = s * 8;

#define EDGE_STEP(EE) do { \
        int2 t = ed[EE]; \
        int col = t.x & 0x3FFFF; \
        int rl  = t.x >> 18; \
        float v = __int_as_float(t.y); \
        uint4 g = xin[(size_t)col * 8 + s]; \
        float* ap = &acc[rl * LST + s8]; \
        lds_fadd(ap + 0, v * blo(g.x)); \
        lds_fadd(ap + 1, v * bhi(g.x)); \
        lds_fadd(ap + 2, v * blo(g.y)); \
        lds_fadd(ap + 3, v * bhi(g.y)); \
        lds_fadd(ap + 4, v * blo(g.z)); \
        lds_fadd(ap + 5, v * bhi(g.z)); \
        lds_fadd(ap + 6, v * blo(g.w)); \
        lds_fadd(ap + 7, v * bhi(g.w)); \
    } while (0)

    int e = bptr[b] + (tid >> 3);
    for (; e + 192 < e1; e += 256) {
        EDGE_STEP(e); EDGE_STEP(e + 64); EDGE_STEP(e + 128); EDGE_STEP(e + 192);
    }
    for (; e < e1; e += 64) EDGE_STEP(e);
#undef EDGE_STEP

    __syncthreads();

    int r0 = b * RPB;
    if (!last) {
        for (int rl = (tid >> 3); rl < RPB; rl += 64) {
            int r = r0 + rl;
            if (r >= NTOT) break;
            int ab = rl * LST + s8;
            uint4 o;
            o.x = (unsigned)benc(acc[ab + 0]) | ((unsigned)benc(acc[ab + 1]) << 16);
            o.y = (unsigned)benc(acc[ab + 2]) | ((unsigned)benc(acc[ab + 3]) << 16);
            o.z = (unsigned)benc(acc[ab + 4]) | ((unsigned)benc(acc[ab + 5]) << 16);
            o.w = (unsigned)benc(acc[ab + 6]) | ((unsigned)benc(acc[ab + 7]) << 16);
            yout[(size_t)r * 8 + s] = o;
        }
    } else {
        for (int rl = (tid >> 3); rl < RPB; rl += 64) {
            int r = r0 + rl;
            if (r >= NTOT) break;
            int ab = rl * LST + s8;
            size_t f4 = (size_t)r * 16 + 2 * s;   // float4 index of comps [8s, 8s+8)
            float4 x0a = (r < NUSERS) ? user[f4]     : item[f4     - (size_t)NUSERS * 16];
            float4 x0b = (r < NUSERS) ? user[f4 + 1] : item[f4 + 1 - (size_t)NUSERS * 16];
            uint4 u1 = y1[(size_t)r * 8 + s];
            uint4 u2 = xin[(size_t)r * 8 + s];   // layer-3 input IS y2
            float4 oa, ob;
            oa.x = 0.25f * (x0a.x + blo(u1.x) + blo(u2.x) + acc[ab + 0]);
            oa.y = 0.25f * (x0a.y + bhi(u1.x) + bhi(u2.x) + acc[ab + 1]);
            oa.z = 0.25f * (x0a.z + blo(u1.y) + blo(u2.y) + acc[ab + 2]);
            oa.w = 0.25f * (x0a.w + bhi(u1.y) + bhi(u2.y) + acc[ab + 3]);
            ob.x = 0.25f * (x0b.x + blo(u1.z) + blo(u2.z) + acc[ab + 4]);
            ob.y = 0.25f * (x0b.y + bhi(u1.z) + bhi(u2.z) + acc[ab + 5]);
            ob.z = 0.25f * (x0b.z + blo(u1.w) + blo(u2.w) + acc[ab + 6]);
            ob.w = 0.25f * (x0b.w + bhi(u1.w) + bhi(u2.w) + acc[ab + 7]);
            out[f4]     = oa;
            out[f4 + 1] = ob;
        }
    }
}

extern "C" void kernel_launch(void* const* d_in, const int* in_sizes, int n_in,
                              void* d_out, int out_size, void* d_ws, size_t ws_size,
                              hipStream_t stream) {
    const float* user = (const float*)d_in[0];
    const float* item = (const float*)d_in[1];
    const float* vals = (const float*)d_in[2];
    const int*   rows = (const int*)d_in[3];
    const int*   cols = (const int*)d_in[4];
    float* out = (float*)d_out;

    // ws layout (~79 MB): tmp 38.4M (in-place cb-sorted edges) | bufA 19.2M |
    // bufB 19.2M | cntmatT 1.2M | runoffT 1.2M | colTotal 2K | bptr 2K
    char* w = (char*)d_ws;
    int2*     tmp      = (int2*)w;     w += (size_t)NNZ_E * 8;
    unsigned* bufA     = (unsigned*)w; w += (size_t)NTOT * DIM * 2;   // x0h, later y2h
    unsigned* bufB     = (unsigned*)w; w += (size_t)NTOT * DIM * 2;   // y1h
    int*      cntmatT  = (int*)w;      w += (size_t)NBUCK * NPART * 4;
    int*      runoffT  = (int*)w;      w += (size_t)NBUCK * NPART * 4;
    int*      colTotal = (int*)w;      w += (size_t)NBUCK * 4;
    int*      bptr     = (int*)w;

    const int blk = 256;
    const int gConv = (NTOT * 32 + blk - 1) / blk;       // 18750

    // Deterministic two-pass counting partition (no global atomics, regular stores)
    partA1_kernel<<<NPART, 512, 0, stream>>>(rows, cntmatT);
    colscan1_kernel<<<NBUCK, 1024, 0, stream>>>(cntmatT, runoffT, colTotal);
    colscan2_kernel<<<1, 512, 0, stream>>>(colTotal, bptr);
    partA2_kernel<<<NPART, 512, 0, stream>>>(rows, cols, vals, runoffT, bptr, tmp);
    partB_kernel<<<NBUCK, 1024, 0, stream>>>(bptr, tmp);

    // Layer input in bf16
    convert_kernel<<<gConv, blk, 0, stream>>>((const float2*)user, (const float2*)item, bufA);

    // 3 propagation layers; layer 3 fuses the stage-mean into out
    spmm2_kernel<<<NBUCK, 512, 0, stream>>>(bptr, tmp, (const uint4*)bufA, (uint4*)bufB,
                                            (const float4*)user, (const float4*)item,
                                            (const uint4*)bufB, (float4*)out, 0); // y1=bufB
    spmm2_kernel<<<NBUCK, 512, 0, stream>>>(bptr, tmp, (const uint4*)bufB, (uint4*)bufA,
                                            (const float4*)user, (const float4*)item,
                                            (const uint4*)bufB, (float4*)out, 0); // y2=bufA
    spmm2_kernel<<<NBUCK, 512, 0, stream>>>(bptr, tmp, (const uint4*)bufA, (uint4*)bufA,
                                            (const float4*)user, (const float4*)item,
                                            (const uint4*)bufB, (float4*)out, 1); // fused mean
}

// Round 3
// 597.076 us; speedup vs baseline: 8.2441x; 8.2185x over previous
//
#include <hip/hip_runtime.h>

// LightGCN on MI355X (gfx950). Round 11.
// R9/R10 post-mortem: identical 1560us with CAS-loop vs native ds_add_f32 =>
// bound by LDS ATOMIC wave-instruction throughput (~200 cy each; 18,750/CU/layer).
// Lesson: no LDS atomics in per-edge paths, ever. Column-band locality itself
// WORKED (FETCH 305->214MB).
// R11: register accumulation + synchronized column sweep, zero LDS in spmm:
//  * each 8-lane oct owns 4 consecutive rows; acc = 8 named float4s (static regs);
//  * edges sorted by (rowgroup=row>>2 major, column-bucket minor), int2 {col|k<<18, fp32 val};
//  * runtime k-select = 4x cndmask + 32 FMAs (~24us/CU/layer VALU - cheap);
//  * 37,504 octs = 4688 waves ~ all-resident -> single in-phase cb sweep (no rounds).
// Partition: partA (row-bucket counting, 586 buckets of 256 rows) -> partB (in-bucket
// cb counting-sort, writes cbptr) -> partB2 (og-hist + cb-segment-sequential stable
// scatter to oct-groups, LDS-staged, in-place in tmp; writes optr).

#define NUSERS 100000
#define NITEMS 50000
#define NTOT   150000
#define DIM    64
#define NNZ_E  4800000

#define RPB     256    // rows per bucket
#define RSH     8
#define NBUCK   586    // ceil(150000/256)
#define NCB     293    // column buckets of 512 cols
#define CSH     9
#define CHUNK_E 8192
#define NPART   ((NNZ_E + CHUNK_E - 1) / CHUNK_E) // 586
#define BCAP    12000  // bucket stage cap (mean 8191, sd ~90 -> +42 sigma)
#define NOCT    (NBUCK * 64)   // 37,504 oct-groups (4 rows each)

__device__ __forceinline__ unsigned short benc(float f) {
    union { float f; unsigned u; } t; t.f = f;
    unsigned r = t.u + 0x7FFFu + ((t.u >> 16) & 1u);   // RNE
    return (unsigned short)(r >> 16);
}
__device__ __forceinline__ float blo(unsigned g) { return __uint_as_float(g << 16); }
__device__ __forceinline__ float bhi(unsigned g) { return __uint_as_float(g & 0xFFFF0000u); }

// ---- Pass 1: per-chunk LDS histogram -> TRANSPOSED count matrix cntmatT[b][p] ----
__global__ void __launch_bounds__(512)
partA1_kernel(const int* __restrict__ rows, int* __restrict__ cntmatT) {
    __shared__ int l[NBUCK];
    int p = blockIdx.x;
    int c0 = p * CHUNK_E;
    int c1 = c0 + CHUNK_E; if (c1 > NNZ_E) c1 = NNZ_E;
    for (int k = threadIdx.x; k < NBUCK; k += 512) l[k] = 0;
    __syncthreads();
    for (int e = c0 + threadIdx.x; e < c1; e += 512)
        atomicAdd(&l[rows[e] >> RSH], 1);
    __syncthreads();
    for (int k = threadIdx.x; k < NBUCK; k += 512)
        cntmatT[(size_t)k * NPART + p] = l[k];
}

// ---- Per-bucket run-offset scan: block b scans cntmatT[b][0..NPART) ----
__global__ void __launch_bounds__(1024)
colscan1_kernel(const int* __restrict__ cntmatT, int* __restrict__ runoffT,
                int* __restrict__ colTotal) {
    __shared__ int t[1024];
    int b = blockIdx.x;
    int tid = threadIdx.x;
    int v = (tid < NPART) ? cntmatT[(size_t)b * NPART + tid] : 0;
    t[tid] = v;
    __syncthreads();
    for (int ofs = 1; ofs < 1024; ofs <<= 1) {
        int a = (tid >= ofs) ? t[tid - ofs] : 0;
        __syncthreads();
        t[tid] += a;
        __syncthreads();
    }
    if (tid < NPART) runoffT[(size_t)b * NPART + tid] = t[tid] - v;
    if (tid == NPART - 1) colTotal[b] = t[tid];
}

// ---- Exclusive scan of colTotal (NBUCK=586) -> bptr[NBUCK+1] ----
__global__ void __launch_bounds__(1024)
colscan2_kernel(const int* __restrict__ colTotal, int* __restrict__ bptr) {
    __shared__ int t[1024];
    int tid = threadIdx.x;
    int v = (tid < NBUCK) ? colTotal[tid] : 0;
    t[tid] = v;
    __syncthreads();
    for (int ofs = 1; ofs < 1024; ofs <<= 1) {
        int a = (tid >= ofs) ? t[tid - ofs] : 0;
        __syncthreads();
        t[tid] += a;
        __syncthreads();
    }
    if (tid < NBUCK) bptr[tid] = t[tid] - v;
    if (tid == 1023) bptr[NBUCK] = t[1023];
}

// ---- Pass 2: scatter into bucket runs. tmp: x = col | rl<<18 (rl<256), y = fp32 val ----
__global__ void __launch_bounds__(512)
partA2_kernel(const int* __restrict__ rows, const int* __restrict__ cols,
              const float* __restrict__ vals, const int* __restrict__ runoffT,
              const int* __restrict__ bptr, int2* __restrict__ tmp) {
    __shared__ int cur[NBUCK];
    int p = blockIdx.x;
    int c0 = p * CHUNK_E;
    int c1 = c0 + CHUNK_E; if (c1 > NNZ_E) c1 = NNZ_E;
    for (int k = threadIdx.x; k < NBUCK; k += 512)
        cur[k] = bptr[k] + runoffT[(size_t)k * NPART + p];
    __syncthreads();
    for (int e = c0 + threadIdx.x; e < c1; e += 512) {
        int r = rows[e];
        int b = r >> RSH, rl = r & (RPB - 1);
        int q = atomicAdd(&cur[b], 1);
        tmp[q] = make_int2(cols[e] | (rl << 18), __float_as_int(vals[e]));
    }
}

// ---- Phase B: per-bucket counting sort by COLUMN bucket, in place; writes cbptr ----
__global__ void __launch_bounds__(1024)
partB_kernel(const int* __restrict__ bptr, int2* __restrict__ tmp,
             int* __restrict__ cbptr) {
    __shared__ int cnt[NCB];
    __shared__ int cur[NCB];
    __shared__ int2 buf[BCAP];
    int b = blockIdx.x;
    int bb0 = bptr[b];
    int nb = bptr[b + 1] - bb0;
    int tid = threadIdx.x;
    if (tid < NCB) cnt[tid] = 0;
    __syncthreads();
    for (int k = tid; k < nb; k += 1024) {
        int2 t = tmp[bb0 + k];
        buf[k] = t;
        atomicAdd(&cnt[(t.x & 0x3FFFF) >> CSH], 1);
    }
    __syncthreads();
    int v = 0;
    if (tid < NCB) { v = cnt[tid]; cur[tid] = v; }
    __syncthreads();
    for (int ofs = 1; ofs < 512; ofs <<= 1) {
        int a = (tid < NCB && tid >= ofs) ? cur[tid - ofs] : 0;
        __syncthreads();
        if (tid < NCB) cur[tid] += a;
        __syncthreads();
    }
    if (tid < NCB) {
        int ex = cur[tid] - v;
        cur[tid] = ex;
        cbptr[(size_t)b * (NCB + 1) + tid] = ex;
    }
    if (tid == 0) cbptr[(size_t)b * (NCB + 1) + NCB] = nb;
    __syncthreads();
    for (int k = tid; k < nb; k += 1024) {
        int2 t = buf[k];
        int q = atomicAdd(&cur[(t.x & 0x3FFFF) >> CSH], 1);
        tmp[bb0 + q] = t;            // safe: whole bucket staged in LDS first
    }
}

// ---- Phase B2: stable (cb-segment-sequential) counting sort by oct-group og=rl>>2 ----
// In-place in tmp via LDS stage. Output word: x = col | (k=rl&3)<<18, y = fp32 val.
__global__ void __launch_bounds__(1024)
partB2_kernel(const int* __restrict__ bptr, const int* __restrict__ cbptr,
              int2* __restrict__ tmp, int* __restrict__ optr) {
    __shared__ int cnt[64];
    __shared__ int cur[64];
    __shared__ int cbq[NCB + 1];
    __shared__ int2 buf[BCAP];
    int b = blockIdx.x;
    int bb0 = bptr[b];
    int nb = bptr[b + 1] - bb0;
    int tid = threadIdx.x;
    if (tid <= NCB) cbq[tid] = cbptr[(size_t)b * (NCB + 1) + tid];
    if (tid < 64) cnt[tid] = 0;
    __syncthreads();
    for (int k = tid; k < nb; k += 1024) {
        int2 t = tmp[bb0 + k];
        buf[k] = t;
        atomicAdd(&cnt[((unsigned)t.x) >> 20], 1);   // og = rl>>2 = bits 20..25
    }
    __syncthreads();
    int v = 0;
    if (tid < 64) { v = cnt[tid]; cur[tid] = v; }
    __syncthreads();
    for (int ofs = 1; ofs < 64; ofs <<= 1) {
        int a = (tid < 64 && tid >= ofs) ? cur[tid - ofs] : 0;
        __syncthreads();
        if (tid < 64) cur[tid] += a;
        __syncthreads();
    }
    if (tid < 64) {
        int ex = cur[tid] - v;
        cur[tid] = ex;
        optr[b * 64 + tid] = bb0 + ex;
    }
    if (b == NBUCK - 1 && tid == 0) optr[NBUCK * 64] = bb0 + nb;
    __syncthreads();
    // 8 cb-segments per barrier: within-row disorder window <= 8 cb (~0.5MB band blur)
    for (int s0 = 0; s0 < NCB; s0 += 8) {
        int hiidx = (s0 + 8 < NCB) ? s0 + 8 : NCB;
        int lo = cbq[s0], hi = cbq[hiidx];
        for (int t2 = lo + tid; t2 < hi; t2 += 1024) {
            int2 t = buf[t2];
            unsigned rl = ((unsigned)t.x) >> 18;
            int q = atomicAdd(&cur[rl >> 2], 1);
            tmp[bb0 + q] = make_int2((t.x & 0x3FFFF) | ((int)(rl & 3) << 18), t.y);
        }
        __syncthreads();
    }
}

// ---- x0h bf16-packed: uint j of row r = comps (2j, 2j+1) ----
__global__ void convert_kernel(const float2* __restrict__ user, const float2* __restrict__ item,
                               unsigned* __restrict__ xh2) {
    int i = blockIdx.x * blockDim.x + threadIdx.x;   // = row*32 + j
    if (i >= NTOT * 32) return;
    float2 v = (i < NUSERS * 32) ? user[i] : item[i - NUSERS * 32];
    xh2[i] = (unsigned)benc(v.x) | ((unsigned)benc(v.y) << 16);
}

// ---- SpMM: 8-lane oct owns 4 rows; register acc; merged cb-sorted edge list ----
__global__ void __launch_bounds__(256)
spmm4_kernel(const int* __restrict__ optr, const int2* __restrict__ ed,
             const uint4* __restrict__ xin, uint4* __restrict__ yout,
             const float4* __restrict__ user, const float4* __restrict__ item,
             const uint4* __restrict__ y1, float4* __restrict__ out, int last) {
    int wid  = blockIdx.x * 4 + (threadIdx.x >> 6);
    int lane = threadIdx.x & 63;
    int g    = wid * 8 + (lane >> 3);          // oct-group id, 0..NOCT
    int s    = lane & 7;
    int i    = optr[g];
    int end  = optr[g + 1];
    float4 A00 = {0,0,0,0}, A01 = {0,0,0,0};
    float4 A10 = {0,0,0,0}, A11 = {0,0,0,0};
    float4 A20 = {0,0,0,0}, A21 = {0,0,0,0};
    float4 A30 = {0,0,0,0}, A31 = {0,0,0,0};

#define PROC(E, G) do { \
        float v  = __int_as_float((E).y); \
        int   k  = ((E).x >> 18) & 3; \
        float s0 = (k == 0) ? v : 0.f, s1 = (k == 1) ? v : 0.f; \
        float s2 = (k == 2) ? v : 0.f, s3 = (k == 3) ? v : 0.f; \
        float f0 = blo((G).x), f1 = bhi((G).x), f2 = blo((G).y), f3 = bhi((G).y); \
        float f4_ = blo((G).z), f5 = bhi((G).z), f6 = blo((G).w), f7 = bhi((G).w); \
        A00.x += s0*f0; A00.y += s0*f1; A00.z += s0*f2; A00.w += s0*f3; \
        A01.x += s0*f4_; A01.y += s0*f5; A01.z += s0*f6; A01.w += s0*f7; \
        A10.x += s1*f0; A10.y += s1*f1; A10.z += s1*f2; A10.w += s1*f3; \
        A11.x += s1*f4_; A11.y += s1*f5; A11.z += s1*f6; A11.w += s1*f7; \
        A20.x += s2*f0; A20.y += s2*f1; A20.z += s2*f2; A20.w += s2*f3; \
        A21.x += s2*f4_; A21.y += s2*f5; A21.z += s2*f6; A21.w += s2*f7; \
        A30.x += s3*f0; A30.y += s3*f1; A30.z += s3*f2; A30.w += s3*f3; \
        A31.x += s3*f4_; A31.y += s3*f5; A31.z += s3*f6; A31.w += s3*f7; \
    } while (0)

    for (; i + 4 <= end; i += 4) {
        int2 e0 = ed[i], e1 = ed[i + 1], e2 = ed[i + 2], e3 = ed[i + 3];
        uint4 g0 = xin[(size_t)(e0.x & 0x3FFFF) * 8 + s];
        uint4 g1 = xin[(size_t)(e1.x & 0x3FFFF) * 8 + s];
        uint4 g2 = xin[(size_t)(e2.x & 0x3FFFF) * 8 + s];
        uint4 g3 = xin[(size_t)(e3.x & 0x3FFFF) * 8 + s];
        PROC(e0, g0); PROC(e1, g1); PROC(e2, g2); PROC(e3, g3);
    }
    for (; i < end; ++i) {
        int2 e = ed[i];
        uint4 gg = xin[(size_t)(e.x & 0x3FFFF) * 8 + s];
        PROC(e, gg);
    }
#undef PROC

    if (!last) {
#define EPI(K, AK0, AK1) do { \
        int r = g * 4 + (K); \
        if (r < NTOT) { \
            uint4 o; \
            o.x = (unsigned)benc(AK0.x) | ((unsigned)benc(AK0.y) << 16); \
            o.y = (unsigned)benc(AK0.z) | ((unsigned)benc(AK0.w) << 16); \
            o.z = (unsigned)benc(AK1.x) | ((unsigned)benc(AK1.y) << 16); \
            o.w = (unsigned)benc(AK1.z) | ((unsigned)benc(AK1.w) << 16); \
            yout[(size_t)r * 8 + s] = o; \
        } \
    } while (0)
        EPI(0, A00, A01); EPI(1, A10, A11); EPI(2, A20, A21); EPI(3, A30, A31);
#undef EPI
    } else {
#define EPI(K, AK0, AK1) do { \
        int r = g * 4 + (K); \
        if (r < NTOT) { \
            size_t f4 = (size_t)r * 16 + 2 * s; \
            float4 x0a = (r < NUSERS) ? user[f4]     : item[f4     - (size_t)NUSERS * 16]; \
            float4 x0b = (r < NUSERS) ? user[f4 + 1] : item[f4 + 1 - (size_t)NUSERS * 16]; \
            uint4 u1 = y1[(size_t)r * 8 + s]; \
            uint4 u2 = xin[(size_t)r * 8 + s]; \
            float4 oa, ob; \
            oa.x = 0.25f * (x0a.x + blo(u1.x) + blo(u2.x) + AK0.x); \
            oa.y = 0.25f * (x0a.y + bhi(u1.x) + bhi(u2.x) + AK0.y); \
            oa.z = 0.25f * (x0a.z + blo(u1.y) + blo(u2.y) + AK0.z); \
            oa.w = 0.25f * (x0a.w + bhi(u1.y) + bhi(u2.y) + AK0.w); \
            ob.x = 0.25f * (x0b.x + blo(u1.z) + blo(u2.z) + AK1.x); \
            ob.y = 0.25f * (x0b.y + bhi(u1.z) + bhi(u2.z) + AK1.y); \
            ob.z = 0.25f * (x0b.z + blo(u1.w) + blo(u2.w) + AK1.z); \
            ob.w = 0.25f * (x0b.w + bhi(u1.w) + bhi(u2.w) + AK1.w); \
            out[f4]     = oa; \
            out[f4 + 1] = ob; \
        } \
    } while (0)
        EPI(0, A00, A01); EPI(1, A10, A11); EPI(2, A20, A21); EPI(3, A30, A31);
#undef EPI
    }
}

extern "C" void kernel_launch(void* const* d_in, const int* in_sizes, int n_in,
                              void* d_out, int out_size, void* d_ws, size_t ws_size,
                              hipStream_t stream) {
    const float* user = (const float*)d_in[0];
    const float* item = (const float*)d_in[1];
    const float* vals = (const float*)d_in[2];
    const int*   rows = (const int*)d_in[3];
    const int*   cols = (const int*)d_in[4];
    float* out = (float*)d_out;

    // ws layout (~80 MB): tmp 38.4M | bufA 19.2M | bufB 19.2M |
    // cntmatT 1.37M | runoffT 1.37M | cbptr 689K | optr 150K | colTotal | bptr
    char* w = (char*)d_ws;
    int2*     tmp      = (int2*)w;     w += (size_t)NNZ_E * 8;
    unsigned* bufA     = (unsigned*)w; w += (size_t)NTOT * DIM * 2;   // x0h, later y2h
    unsigned* bufB     = (unsigned*)w; w += (size_t)NTOT * DIM * 2;   // y1h
    int*      cntmatT  = (int*)w;      w += (size_t)NBUCK * NPART * 4;
    int*      runoffT  = (int*)w;      w += (size_t)NBUCK * NPART * 4;
    int*      cbptr    = (int*)w;      w += (size_t)NBUCK * (NCB + 1) * 4;
    int*      optr     = (int*)w;      w += (size_t)(NOCT + 1) * 4;
    int*      colTotal = (int*)w;      w += (size_t)NBUCK * 4;
    int*      bptr     = (int*)w;

    const int blk = 256;
    const int gConv = (NTOT * 32 + blk - 1) / blk;       // 18750
    const int gSpmm = NOCT / 32;                         // 1172 (4 waves, 8 octs/wave)

    partA1_kernel<<<NPART, 512, 0, stream>>>(rows, cntmatT);
    colscan1_kernel<<<NBUCK, 1024, 0, stream>>>(cntmatT, runoffT, colTotal);
    colscan2_kernel<<<1, 1024, 0, stream>>>(colTotal, bptr);
    partA2_kernel<<<NPART, 512, 0, stream>>>(rows, cols, vals, runoffT, bptr, tmp);
    partB_kernel<<<NBUCK, 1024, 0, stream>>>(bptr, tmp, cbptr);
    partB2_kernel<<<NBUCK, 1024, 0, stream>>>(bptr, cbptr, tmp, optr);

    convert_kernel<<<gConv, blk, 0, stream>>>((const float2*)user, (const float2*)item, bufA);

    spmm4_kernel<<<gSpmm, blk, 0, stream>>>(optr, tmp, (const uint4*)bufA, (uint4*)bufB,
                                            (const float4*)user, (const float4*)item,
                                            (const uint4*)bufB, (float4*)out, 0); // y1=bufB
    spmm4_kernel<<<gSpmm, blk, 0, stream>>>(optr, tmp, (const uint4*)bufB, (uint4*)bufA,
                                            (const float4*)user, (const float4*)item,
                                            (const uint4*)bufB, (float4*)out, 0); // y2=bufA
    spmm4_kernel<<<gSpmm, blk, 0, stream>>>(optr, tmp, (const uint4*)bufA, (uint4*)bufA,
                                            (const float4*)user, (const float4*)item,
                                            (const uint4*)bufB, (float4*)out, 1); // fused mean
}

// Round 4
// 492.231 us; speedup vs baseline: 10.0001x; 1.2130x over previous
//
#include <hip/hip_runtime.h>

// LightGCN on MI355X (gfx950). Round 12.
// R11 worked (597us; spmm off top-5). New #1: partA2 118us with WRITE 123MB for
// 38.4MB logical = 3.2x line-granularity write amp (8B stores into 586 runs,
// ~14 edges/run-segment per 8K chunk). Fixes this round:
//  1) CHUNK_E 16384 (NPART 293): run segments ~224B -> write amp ~1.6x.
//  2) partB+partB2 fused into ONE composite-key counting sort (key = og*37 +
//     (col>>12), 2368 bins). No LDS staging: output is a different array (fin),
//     bucket window 64KB is L2-resident for the 2nd read. Kills a 77MB pass and
//     one per-edge LDS-atomic pass (~200cy/wave-instr floor, R9/R10 lesson).
//  3) fin edges are 4B {val12|k2|col18} (val RNE to 12 bits, clamp 4095):
//     spmm edge stream 38.4->19.2MB/layer. absmax is bf16-ulp-dominated
//     (identical 0.03125 with fp32 and 14b vals), ~1e-4 added noise is safe.
// spmm4 structure unchanged from R11 (register acc, 4 rows/oct, cb8-band sweep).

#define NUSERS 100000
#define NITEMS 50000
#define NTOT   150000
#define DIM    64
#define NNZ_E  4800000

#define RPB     256    // rows per bucket
#define RSH     8
#define NBUCK   586    // ceil(150000/256)
#define CHUNK_E 16384
#define NPART   ((NNZ_E + CHUNK_E - 1) / CHUNK_E) // 293
#define NBIN    (64 * 37)   // og (rl>>2) x cb8 (col>>12); col<150000 -> col>>12 < 37
#define NOCT    (NBUCK * 64)   // 37,504 oct-groups (4 rows each)

__device__ __forceinline__ unsigned short benc(float f) {
    union { float f; unsigned u; } t; t.f = f;
    unsigned r = t.u + 0x7FFFu + ((t.u >> 16) & 1u);   // RNE
    return (unsigned short)(r >> 16);
}
__device__ __forceinline__ float blo(unsigned g) { return __uint_as_float(g << 16); }
__device__ __forceinline__ float bhi(unsigned g) { return __uint_as_float(g & 0xFFFF0000u); }

// ---- Pass 1: per-chunk LDS histogram -> TRANSPOSED count matrix cntmatT[b][p] ----
__global__ void __launch_bounds__(1024)
partA1_kernel(const int* __restrict__ rows, int* __restrict__ cntmatT) {
    __shared__ int l[NBUCK];
    int p = blockIdx.x;
    int c0 = p * CHUNK_E;
    int c1 = c0 + CHUNK_E; if (c1 > NNZ_E) c1 = NNZ_E;
    for (int k = threadIdx.x; k < NBUCK; k += 1024) l[k] = 0;
    __syncthreads();
    for (int e = c0 + threadIdx.x; e < c1; e += 1024)
        atomicAdd(&l[rows[e] >> RSH], 1);
    __syncthreads();
    for (int k = threadIdx.x; k < NBUCK; k += 1024)
        cntmatT[(size_t)k * NPART + p] = l[k];
}

// ---- Per-bucket run-offset scan: block b scans cntmatT[b][0..NPART) (NPART=293) ----
__global__ void __launch_bounds__(512)
colscan1_kernel(const int* __restrict__ cntmatT, int* __restrict__ runoffT,
                int* __restrict__ colTotal) {
    __shared__ int t[512];
    int b = blockIdx.x;
    int tid = threadIdx.x;
    int v = (tid < NPART) ? cntmatT[(size_t)b * NPART + tid] : 0;
    t[tid] = v;
    __syncthreads();
    for (int ofs = 1; ofs < 512; ofs <<= 1) {
        int a = (tid >= ofs) ? t[tid - ofs] : 0;
        __syncthreads();
        t[tid] += a;
        __syncthreads();
    }
    if (tid < NPART) runoffT[(size_t)b * NPART + tid] = t[tid] - v;
    if (tid == NPART - 1) colTotal[b] = t[tid];
}

// ---- Exclusive scan of colTotal (NBUCK=586) -> bptr[NBUCK+1] ----
__global__ void __launch_bounds__(1024)
colscan2_kernel(const int* __restrict__ colTotal, int* __restrict__ bptr) {
    __shared__ int t[1024];
    int tid = threadIdx.x;
    int v = (tid < NBUCK) ? colTotal[tid] : 0;
    t[tid] = v;
    __syncthreads();
    for (int ofs = 1; ofs < 1024; ofs <<= 1) {
        int a = (tid >= ofs) ? t[tid - ofs] : 0;
        __syncthreads();
        t[tid] += a;
        __syncthreads();
    }
    if (tid < NBUCK) bptr[tid] = t[tid] - v;
    if (tid == 1023) bptr[NBUCK] = t[1023];
}

// ---- Pass 2: scatter into bucket runs. tmp: x = col | rl<<18 (rl<256), y = fp32 val ----
__global__ void __launch_bounds__(1024)
partA2_kernel(const int* __restrict__ rows, const int* __restrict__ cols,
              const float* __restrict__ vals, const int* __restrict__ runoffT,
              const int* __restrict__ bptr, int2* __restrict__ tmp) {
    __shared__ int cur[NBUCK];
    int p = blockIdx.x;
    int c0 = p * CHUNK_E;
    int c1 = c0 + CHUNK_E; if (c1 > NNZ_E) c1 = NNZ_E;
    for (int k = threadIdx.x; k < NBUCK; k += 1024)
        cur[k] = bptr[k] + runoffT[(size_t)k * NPART + p];
    __syncthreads();
    for (int e = c0 + threadIdx.x; e < c1; e += 1024) {
        int r = rows[e];
        int b = r >> RSH, rl = r & (RPB - 1);
        int q = atomicAdd(&cur[b], 1);
        tmp[q] = make_int2(cols[e] | (rl << 18), __float_as_int(vals[e]));
    }
}

// ---- Fused Phase B: per-bucket counting sort by composite key (og, col>>12) ----
// Reads tmp (bucket window 64KB, 2nd read L2-hits), writes 4B fin + optr.
// fin word: col[0:17] | k=rl&3 [18:19] | val12 [20:31].
__global__ void __launch_bounds__(1024)
partBF_kernel(const int* __restrict__ bptr, const int2* __restrict__ tmp,
              unsigned* __restrict__ fin, int* __restrict__ optr) {
    __shared__ int cnt[NBIN];
    __shared__ int base[NBIN];
    __shared__ int st[1024];
    int b = blockIdx.x;
    int bb0 = bptr[b];
    int nb = bptr[b + 1] - bb0;
    int tid = threadIdx.x;
    for (int k = tid; k < NBIN; k += 1024) cnt[k] = 0;
    __syncthreads();
    for (int k = tid; k < nb; k += 1024) {
        int x = tmp[bb0 + k].x;
        int key = ((x >> 20) & 63) * 37 + ((x & 0x3FFFF) >> 12);
        atomicAdd(&cnt[key], 1);
    }
    __syncthreads();
    // hierarchical exclusive scan of 2368 bins: 3 bins/thread + 1024-wide block scan
    int t0 = tid * 3;
    int c0 = (t0     < NBIN) ? cnt[t0]     : 0;
    int c1 = (t0 + 1 < NBIN) ? cnt[t0 + 1] : 0;
    int c2 = (t0 + 2 < NBIN) ? cnt[t0 + 2] : 0;
    int s = c0 + c1 + c2;
    st[tid] = s;
    __syncthreads();
    for (int ofs = 1; ofs < 1024; ofs <<= 1) {
        int a = (tid >= ofs) ? st[tid - ofs] : 0;
        __syncthreads();
        st[tid] += a;
        __syncthreads();
    }
    int P = st[tid] - s;
    if (t0     < NBIN) base[t0]     = P;
    if (t0 + 1 < NBIN) base[t0 + 1] = P + c0;
    if (t0 + 2 < NBIN) base[t0 + 2] = P + c0 + c1;
    __syncthreads();
    if (tid < 64) optr[b * 64 + tid] = bb0 + base[tid * 37];
    if (b == NBUCK - 1 && tid == 0) optr[NBUCK * 64] = bb0 + nb;
    __syncthreads();   // optr reads base before the scatter mutates it
    for (int k = tid; k < nb; k += 1024) {
        int2 t = tmp[bb0 + k];
        int x = t.x;
        int key = ((x >> 20) & 63) * 37 + ((x & 0x3FFFF) >> 12);
        int q = atomicAdd(&base[key], 1);
        unsigned qq = (unsigned)__float2int_rn(__int_as_float(t.y) * 4096.f);
        if (qq > 4095u) qq = 4095u;
        fin[bb0 + q] = ((unsigned)x & 0xFFFFFu) | (qq << 20);
    }
}

// ---- x0h bf16-packed: uint j of row r = comps (2j, 2j+1) ----
__global__ void convert_kernel(const float2* __restrict__ user, const float2* __restrict__ item,
                               unsigned* __restrict__ xh2) {
    int i = blockIdx.x * blockDim.x + threadIdx.x;   // = row*32 + j
    if (i >= NTOT * 32) return;
    float2 v = (i < NUSERS * 32) ? user[i] : item[i - NUSERS * 32];
    xh2[i] = (unsigned)benc(v.x) | ((unsigned)benc(v.y) << 16);
}

// ---- SpMM: 8-lane oct owns 4 rows; register acc; 4B cb8-band-sorted edges ----
__global__ void __launch_bounds__(256)
spmm4_kernel(const int* __restrict__ optr, const unsigned* __restrict__ ed,
             const uint4* __restrict__ xin, uint4* __restrict__ yout,
             const float4* __restrict__ user, const float4* __restrict__ item,
             const uint4* __restrict__ y1, float4* __restrict__ out, int last) {
    int wid  = blockIdx.x * 4 + (threadIdx.x >> 6);
    int lane = threadIdx.x & 63;
    int g    = wid * 8 + (lane >> 3);          // oct-group id, 0..NOCT
    int s    = lane & 7;
    int i    = optr[g];
    int end  = optr[g + 1];
    const float SCL = 1.f / 4096.f;
    float4 A00 = {0,0,0,0}, A01 = {0,0,0,0};
    float4 A10 = {0,0,0,0}, A11 = {0,0,0,0};
    float4 A20 = {0,0,0,0}, A21 = {0,0,0,0};
    float4 A30 = {0,0,0,0}, A31 = {0,0,0,0};

#define PROC(E, G) do { \
        float v  = (float)((E) >> 20) * SCL; \
        int   k  = ((E) >> 18) & 3; \
        float s0 = (k == 0) ? v : 0.f, s1 = (k == 1) ? v : 0.f; \
        float s2 = (k == 2) ? v : 0.f, s3 = (k == 3) ? v : 0.f; \
        float f0 = blo((G).x), f1 = bhi((G).x), f2 = blo((G).y), f3 = bhi((G).y); \
        float f4_ = blo((G).z), f5 = bhi((G).z), f6 = blo((G).w), f7 = bhi((G).w); \
        A00.x += s0*f0; A00.y += s0*f1; A00.z += s0*f2; A00.w += s0*f3; \
        A01.x += s0*f4_; A01.y += s0*f5; A01.z += s0*f6; A01.w += s0*f7; \
        A10.x += s1*f0; A10.y += s1*f1; A10.z += s1*f2; A10.w += s1*f3; \
        A11.x += s1*f4_; A11.y += s1*f5; A11.z += s1*f6; A11.w += s1*f7; \
        A20.x += s2*f0; A20.y += s2*f1; A20.z += s2*f2; A20.w += s2*f3; \
        A21.x += s2*f4_; A21.y += s2*f5; A21.z += s2*f6; A21.w += s2*f7; \
        A30.x += s3*f0; A30.y += s3*f1; A30.z += s3*f2; A30.w += s3*f3; \
        A31.x += s3*f4_; A31.y += s3*f5; A31.z += s3*f6; A31.w += s3*f7; \
    } while (0)

    for (; i + 4 <= end; i += 4) {
        unsigned e0 = ed[i], e1 = ed[i + 1], e2 = ed[i + 2], e3 = ed[i + 3];
        uint4 g0 = xin[(size_t)(e0 & 0x3FFFF) * 8 + s];
        uint4 g1 = xin[(size_t)(e1 & 0x3FFFF) * 8 + s];
        uint4 g2 = xin[(size_t)(e2 & 0x3FFFF) * 8 + s];
        uint4 g3 = xin[(size_t)(e3 & 0x3FFFF) * 8 + s];
        PROC(e0, g0); PROC(e1, g1); PROC(e2, g2); PROC(e3, g3);
    }
    for (; i < end; ++i) {
        unsigned e = ed[i];
        uint4 gg = xin[(size_t)(e & 0x3FFFF) * 8 + s];
        PROC(e, gg);
    }
#undef PROC

    if (!last) {
#define EPI(K, AK0, AK1) do { \
        int r = g * 4 + (K); \
        if (r < NTOT) { \
            uint4 o; \
            o.x = (unsigned)benc(AK0.x) | ((unsigned)benc(AK0.y) << 16); \
            o.y = (unsigned)benc(AK0.z) | ((unsigned)benc(AK0.w) << 16); \
            o.z = (unsigned)benc(AK1.x) | ((unsigned)benc(AK1.y) << 16); \
            o.w = (unsigned)benc(AK1.z) | ((unsigned)benc(AK1.w) << 16); \
            yout[(size_t)r * 8 + s] = o; \
        } \
    } while (0)
        EPI(0, A00, A01); EPI(1, A10, A11); EPI(2, A20, A21); EPI(3, A30, A31);
#undef EPI
    } else {
#define EPI(K, AK0, AK1) do { \
        int r = g * 4 + (K); \
        if (r < NTOT) { \
            size_t f4 = (size_t)r * 16 + 2 * s; \
            float4 x0a = (r < NUSERS) ? user[f4]     : item[f4     - (size_t)NUSERS * 16]; \
            float4 x0b = (r < NUSERS) ? user[f4 + 1] : item[f4 + 1 - (size_t)NUSERS * 16]; \
            uint4 u1 = y1[(size_t)r * 8 + s]; \
            uint4 u2 = xin[(size_t)r * 8 + s]; \
            float4 oa, ob; \
            oa.x = 0.25f * (x0a.x + blo(u1.x) + blo(u2.x) + AK0.x); \
            oa.y = 0.25f * (x0a.y + bhi(u1.x) + bhi(u2.x) + AK0.y); \
            oa.z = 0.25f * (x0a.z + blo(u1.y) + blo(u2.y) + AK0.z); \
            oa.w = 0.25f * (x0a.w + bhi(u1.y) + bhi(u2.y) + AK0.w); \
            ob.x = 0.25f * (x0b.x + blo(u1.z) + blo(u2.z) + AK1.x); \
            ob.y = 0.25f * (x0b.y + bhi(u1.z) + bhi(u2.z) + AK1.y); \
            ob.z = 0.25f * (x0b.z + blo(u1.w) + blo(u2.w) + AK1.z); \
            ob.w = 0.25f * (x0b.w + bhi(u1.w) + bhi(u2.w) + AK1.w); \
            out[f4]     = oa; \
            out[f4 + 1] = ob; \
        } \
    } while (0)
        EPI(0, A00, A01); EPI(1, A10, A11); EPI(2, A20, A21); EPI(3, A30, A31);
#undef EPI
    }
}

extern "C" void kernel_launch(void* const* d_in, const int* in_sizes, int n_in,
                              void* d_out, int out_size, void* d_ws, size_t ws_size,
                              hipStream_t stream) {
    const float* user = (const float*)d_in[0];
    const float* item = (const float*)d_in[1];
    const float* vals = (const float*)d_in[2];
    const int*   rows = (const int*)d_in[3];
    const int*   cols = (const int*)d_in[4];
    float* out = (float*)d_out;

    // ws layout (~97 MB): tmp 38.4M | fin 19.2M | bufA 19.2M | bufB 19.2M |
    // cntmatT 687K | runoffT 687K | optr 150K | colTotal | bptr
    char* w = (char*)d_ws;
    int2*     tmp      = (int2*)w;     w += (size_t)NNZ_E * 8;
    unsigned* fin      = (unsigned*)w; w += (size_t)NNZ_E * 4;
    unsigned* bufA     = (unsigned*)w; w += (size_t)NTOT * DIM * 2;   // x0h, later y2h
    unsigned* bufB     = (unsigned*)w; w += (size_t)NTOT * DIM * 2;   // y1h
    int*      cntmatT  = (int*)w;      w += (size_t)NBUCK * NPART * 4;
    int*      runoffT  = (int*)w;      w += (size_t)NBUCK * NPART * 4;
    int*      optr     = (int*)w;      w += (size_t)(NOCT + 1) * 4;
    int*      colTotal = (int*)w;      w += (size_t)NBUCK * 4;
    int*      bptr     = (int*)w;

    const int blk = 256;
    const int gConv = (NTOT * 32 + blk - 1) / blk;       // 18750
    const int gSpmm = NOCT / 32;                         // 1172 (4 waves, 8 octs/wave)

    partA1_kernel<<<NPART, 1024, 0, stream>>>(rows, cntmatT);
    colscan1_kernel<<<NBUCK, 512, 0, stream>>>(cntmatT, runoffT, colTotal);
    colscan2_kernel<<<1, 1024, 0, stream>>>(colTotal, bptr);
    partA2_kernel<<<NPART, 1024, 0, stream>>>(rows, cols, vals, runoffT, bptr, tmp);
    partBF_kernel<<<NBUCK, 1024, 0, stream>>>(bptr, tmp, fin, optr);

    convert_kernel<<<gConv, blk, 0, stream>>>((const float2*)user, (const float2*)item, bufA);

    spmm4_kernel<<<gSpmm, blk, 0, stream>>>(optr, fin, (const uint4*)bufA, (uint4*)bufB,
                                            (const float4*)user, (const float4*)item,
                                            (const uint4*)bufB, (float4*)out, 0); // y1=bufB
    spmm4_kernel<<<gSpmm, blk, 0, stream>>>(optr, fin, (const uint4*)bufB, (uint4*)bufA,
                                            (const float4*)user, (const float4*)item,
                                            (const uint4*)bufB, (float4*)out, 0); // y2=bufA
    spmm4_kernel<<<gSpmm, blk, 0, stream>>>(optr, fin, (const uint4*)bufA, (uint4*)bufA,
                                            (const float4*)user, (const float4*)item,
                                            (const uint4*)bufB, (float4*)out, 1); // fused mean
}

// Round 5
// 475.030 us; speedup vs baseline: 10.3622x; 1.0362x over previous
//
#include <hip/hip_runtime.h>

// LightGCN on MI355X (gfx950). Round 13.
// R12 post-mortem: partA2's write amp (2.9x) is line-EVICTION-bound, not
// segment-length-bound: 586 open run-segments/block x ~37 blocks/XCD = 5.5MB of
// partial write lines > 4MB L2 -> RFO+rewrite regardless of chunk size.
// Fix: partA2 sorts its chunk in LDS and writes back SEQUENTIALLY (amp 1.0);
// partBF gathers each bucket's 586 chunk-segments (reads don't pay RFO) via
// runoffT (bucket-major scan, colscan1) + segoff (chunk-major scan, from partA2)
// + 10-step LDS binary search per edge. partA2 reuses partA1's counts
// (cntmat[p][b], chunk-contiguous) so it has ONE per-edge int-LDS-atomic pass
// (~3cy/lane - int atomics are cheap; only fp LDS atomics are ~25cy/lane).
// Also cb col>>12 -> col>>11 (74 bands) for a tighter spmm column window.
// spmm4 unchanged from R12 to isolate the partition change.

#define NUSERS 100000
#define NITEMS 50000
#define NTOT   150000
#define DIM    64
#define NNZ_E  4800000

#define RPB     256    // rows per bucket
#define RSH     8
#define NBUCK   586    // ceil(150000/256)
#define CHUNK_E 8192
#define NPART   ((NNZ_E + CHUNK_E - 1) / CHUNK_E) // 586
#define NCB     74     // column bands of 2048 cols (150000>>11 = 73)
#define CSH     11
#define NBIN    (64 * NCB)     // 4736: og x cb
#define NOCT    (NBUCK * 64)   // 37,504 oct-groups (4 rows each)

__device__ __forceinline__ unsigned short benc(float f) {
    union { float f; unsigned u; } t; t.f = f;
    unsigned r = t.u + 0x7FFFu + ((t.u >> 16) & 1u);   // RNE
    return (unsigned short)(r >> 16);
}
__device__ __forceinline__ float blo(unsigned g) { return __uint_as_float(g << 16); }
__device__ __forceinline__ float bhi(unsigned g) { return __uint_as_float(g & 0xFFFF0000u); }

// ---- Pass 1: per-chunk LDS histogram -> cntmat[p][b] (chunk-contiguous) ----
__global__ void __launch_bounds__(512)
partA1_kernel(const int* __restrict__ rows, int* __restrict__ cntmat) {
    __shared__ int l[NBUCK];
    int p = blockIdx.x;
    int c0 = p * CHUNK_E;
    int c1 = c0 + CHUNK_E; if (c1 > NNZ_E) c1 = NNZ_E;
    for (int k = threadIdx.x; k < NBUCK; k += 512) l[k] = 0;
    __syncthreads();
    for (int e = c0 + threadIdx.x; e < c1; e += 512)
        atomicAdd(&l[rows[e] >> RSH], 1);
    __syncthreads();
    for (int k = threadIdx.x; k < NBUCK; k += 512)
        cntmat[(size_t)p * NBUCK + k] = l[k];
}

// ---- Per-bucket scan over chunks: runoffT[b][p] excl, [b][NPART] = total ----
__global__ void __launch_bounds__(1024)
colscan1_kernel(const int* __restrict__ cntmat, int* __restrict__ runoffT,
                int* __restrict__ colTotal) {
    __shared__ int t[1024];
    int b = blockIdx.x;
    int tid = threadIdx.x;
    int v = (tid < NPART) ? cntmat[(size_t)tid * NBUCK + b] : 0;
    t[tid] = v;
    __syncthreads();
    for (int ofs = 1; ofs < 1024; ofs <<= 1) {
        int a = (tid >= ofs) ? t[tid - ofs] : 0;
        __syncthreads();
        t[tid] += a;
        __syncthreads();
    }
    if (tid < NPART) runoffT[(size_t)b * (NPART + 1) + tid] = t[tid] - v;
    if (tid == NPART - 1) {
        runoffT[(size_t)b * (NPART + 1) + NPART] = t[tid];
        colTotal[b] = t[tid];
    }
}

// ---- Exclusive scan of colTotal (NBUCK=586) -> bptr[NBUCK+1] ----
__global__ void __launch_bounds__(1024)
colscan2_kernel(const int* __restrict__ colTotal, int* __restrict__ bptr) {
    __shared__ int t[1024];
    int tid = threadIdx.x;
    int v = (tid < NBUCK) ? colTotal[tid] : 0;
    t[tid] = v;
    __syncthreads();
    for (int ofs = 1; ofs < 1024; ofs <<= 1) {
        int a = (tid >= ofs) ? t[tid - ofs] : 0;
        __syncthreads();
        t[tid] += a;
        __syncthreads();
    }
    if (tid < NBUCK) bptr[tid] = t[tid] - v;
    if (tid == 1023) bptr[NBUCK] = t[1023];
}

// ---- Pass 2: LDS bucket-sort of the chunk + SEQUENTIAL writeback (amp 1.0) ----
// tmp[c0..c1) = chunk's edges sorted by bucket. segoff[p][b] = excl offset of
// bucket b's segment within chunk p. tmp word: x = col | rl<<18, y = fp32 val.
__global__ void __launch_bounds__(512)
partA2_kernel(const int* __restrict__ rows, const int* __restrict__ cols,
              const float* __restrict__ vals, const int* __restrict__ cntmat,
              int* __restrict__ segoff, int2* __restrict__ tmp) {
    __shared__ int2 buf[CHUNK_E];          // 64 KB
    __shared__ int cur[NBUCK];
    __shared__ int st[512];
    int p = blockIdx.x;
    int c0 = p * CHUNK_E;
    int c1 = c0 + CHUNK_E; if (c1 > NNZ_E) c1 = NNZ_E;
    int nb = c1 - c0;
    int tid = threadIdx.x;
    // load per-chunk counts (contiguous), 2 bins/thread, exclusive scan
    int t0 = tid * 2;
    int cA = (t0     < NBUCK) ? cntmat[(size_t)p * NBUCK + t0]     : 0;
    int cB = (t0 + 1 < NBUCK) ? cntmat[(size_t)p * NBUCK + t0 + 1] : 0;
    int s = cA + cB;
    st[tid] = s;
    __syncthreads();
    for (int ofs = 1; ofs < 512; ofs <<= 1) {
        int a = (tid >= ofs) ? st[tid - ofs] : 0;
        __syncthreads();
        st[tid] += a;
        __syncthreads();
    }
    int P = st[tid] - s;
    if (t0     < NBUCK) { cur[t0]     = P;      segoff[(size_t)p * NBUCK + t0]     = P; }
    if (t0 + 1 < NBUCK) { cur[t0 + 1] = P + cA; segoff[(size_t)p * NBUCK + t0 + 1] = P + cA; }
    __syncthreads();
    for (int e = c0 + tid; e < c1; e += 512) {
        int r = rows[e];
        int b = r >> RSH, rl = r & (RPB - 1);
        int q = atomicAdd(&cur[b], 1);
        buf[q] = make_int2(cols[e] | (rl << 18), __float_as_int(vals[e]));
    }
    __syncthreads();
    for (int k = tid; k < nb; k += 512)
        tmp[c0 + k] = buf[k];              // fully sequential, coalesced
}

// ---- Fused Phase B: gather bucket segments; counting sort by (og, col>>11) ----
// fin word: col[0:17] | k=rl&3 [18:19] | val12 [20:31].
__global__ void __launch_bounds__(1024)
partBF_kernel(const int* __restrict__ bptr, const int* __restrict__ runoffT,
              const int* __restrict__ segoff, const int2* __restrict__ tmp,
              unsigned* __restrict__ fin, int* __restrict__ optr) {
    __shared__ int cnt[NBIN];
    __shared__ int base[NBIN];
    __shared__ int st[1024];
    __shared__ int runoff[NPART + 1];
    __shared__ int soff[NPART];
    int b = blockIdx.x;
    int bb0 = bptr[b];
    int tid = threadIdx.x;
    for (int k = tid; k < NBIN; k += 1024) cnt[k] = 0;
    if (tid <= NPART) runoff[tid] = runoffT[(size_t)b * (NPART + 1) + tid];
    if (tid < NPART)  soff[tid]   = segoff[(size_t)tid * NBUCK + b];
    __syncthreads();
    int nb = runoff[NPART];
    // pass 1: histogram composite keys
    for (int j = tid; j < nb; j += 1024) {
        int lo = 0, hi = NPART;
        while (hi - lo > 1) { int mid = (lo + hi) >> 1; if (runoff[mid] <= j) lo = mid; else hi = mid; }
        int src = lo * CHUNK_E + soff[lo] + (j - runoff[lo]);
        int x = tmp[src].x;
        int key = ((x >> 20) & 63) * NCB + ((x & 0x3FFFF) >> CSH);
        atomicAdd(&cnt[key], 1);
    }
    __syncthreads();
    // exclusive scan of 4736 bins: 5 bins/thread + block scan
    int t0 = tid * 5;
    int c0 = (t0     < NBIN) ? cnt[t0]     : 0;
    int c1 = (t0 + 1 < NBIN) ? cnt[t0 + 1] : 0;
    int c2 = (t0 + 2 < NBIN) ? cnt[t0 + 2] : 0;
    int c3 = (t0 + 3 < NBIN) ? cnt[t0 + 3] : 0;
    int c4 = (t0 + 4 < NBIN) ? cnt[t0 + 4] : 0;
    int s = c0 + c1 + c2 + c3 + c4;
    st[tid] = s;
    __syncthreads();
    for (int ofs = 1; ofs < 1024; ofs <<= 1) {
        int a = (tid >= ofs) ? st[tid - ofs] : 0;
        __syncthreads();
        st[tid] += a;
        __syncthreads();
    }
    int P = st[tid] - s;
    if (t0     < NBIN) base[t0]     = P;
    if (t0 + 1 < NBIN) base[t0 + 1] = P + c0;
    if (t0 + 2 < NBIN) base[t0 + 2] = P + c0 + c1;
    if (t0 + 3 < NBIN) base[t0 + 3] = P + c0 + c1 + c2;
    if (t0 + 4 < NBIN) base[t0 + 4] = P + c0 + c1 + c2 + c3;
    __syncthreads();
    if (tid < 64) optr[b * 64 + tid] = bb0 + base[tid * NCB];
    if (b == NBUCK - 1 && tid == 0) optr[NBUCK * 64] = bb0 + nb;
    __syncthreads();   // optr snapshot of base before scatter mutates it
    // pass 2: gather again, scatter to fin (4B, quantized val)
    for (int j = tid; j < nb; j += 1024) {
        int lo = 0, hi = NPART;
        while (hi - lo > 1) { int mid = (lo + hi) >> 1; if (runoff[mid] <= j) lo = mid; else hi = mid; }
        int src = lo * CHUNK_E + soff[lo] + (j - runoff[lo]);
        int2 t = tmp[src];
        int x = t.x;
        int key = ((x >> 20) & 63) * NCB + ((x & 0x3FFFF) >> CSH);
        int q = atomicAdd(&base[key], 1);
        unsigned qq = (unsigned)__float2int_rn(__int_as_float(t.y) * 4096.f);
        if (qq > 4095u) qq = 4095u;
        fin[bb0 + q] = ((unsigned)x & 0xFFFFFu) | (qq << 20);
    }
}

// ---- x0h bf16-packed: uint j of row r = comps (2j, 2j+1) ----
__global__ void convert_kernel(const float2* __restrict__ user, const float2* __restrict__ item,
                               unsigned* __restrict__ xh2) {
    int i = blockIdx.x * blockDim.x + threadIdx.x;   // = row*32 + j
    if (i >= NTOT * 32) return;
    float2 v = (i < NUSERS * 32) ? user[i] : item[i - NUSERS * 32];
    xh2[i] = (unsigned)benc(v.x) | ((unsigned)benc(v.y) << 16);
}

// ---- SpMM: 8-lane oct owns 4 rows; register acc; 4B cb-band-sorted edges ----
__global__ void __launch_bounds__(256)
spmm4_kernel(const int* __restrict__ optr, const unsigned* __restrict__ ed,
             const uint4* __restrict__ xin, uint4* __restrict__ yout,
             const float4* __restrict__ user, const float4* __restrict__ item,
             const uint4* __restrict__ y1, float4* __restrict__ out, int last) {
    int wid  = blockIdx.x * 4 + (threadIdx.x >> 6);
    int lane = threadIdx.x & 63;
    int g    = wid * 8 + (lane >> 3);          // oct-group id, 0..NOCT
    int s    = lane & 7;
    int i    = optr[g];
    int end  = optr[g + 1];
    const float SCL = 1.f / 4096.f;
    float4 A00 = {0,0,0,0}, A01 = {0,0,0,0};
    float4 A10 = {0,0,0,0}, A11 = {0,0,0,0};
    float4 A20 = {0,0,0,0}, A21 = {0,0,0,0};
    float4 A30 = {0,0,0,0}, A31 = {0,0,0,0};

#define PROC(E, G) do { \
        float v  = (float)((E) >> 20) * SCL; \
        int   k  = ((E) >> 18) & 3; \
        float s0 = (k == 0) ? v : 0.f, s1 = (k == 1) ? v : 0.f; \
        float s2 = (k == 2) ? v : 0.f, s3 = (k == 3) ? v : 0.f; \
        float f0 = blo((G).x), f1 = bhi((G).x), f2 = blo((G).y), f3 = bhi((G).y); \
        float f4_ = blo((G).z), f5 = bhi((G).z), f6 = blo((G).w), f7 = bhi((G).w); \
        A00.x += s0*f0; A00.y += s0*f1; A00.z += s0*f2; A00.w += s0*f3; \
        A01.x += s0*f4_; A01.y += s0*f5; A01.z += s0*f6; A01.w += s0*f7; \
        A10.x += s1*f0; A10.y += s1*f1; A10.z += s1*f2; A10.w += s1*f3; \
        A11.x += s1*f4_; A11.y += s1*f5; A11.z += s1*f6; A11.w += s1*f7; \
        A20.x += s2*f0; A20.y += s2*f1; A20.z += s2*f2; A20.w += s2*f3; \
        A21.x += s2*f4_; A21.y += s2*f5; A21.z += s2*f6; A21.w += s2*f7; \
        A30.x += s3*f0; A30.y += s3*f1; A30.z += s3*f2; A30.w += s3*f3; \
        A31.x += s3*f4_; A31.y += s3*f5; A31.z += s3*f6; A31.w += s3*f7; \
    } while (0)

    for (; i + 4 <= end; i += 4) {
        unsigned e0 = ed[i], e1 = ed[i + 1], e2 = ed[i + 2], e3 = ed[i + 3];
        uint4 g0 = xin[(size_t)(e0 & 0x3FFFF) * 8 + s];
        uint4 g1 = xin[(size_t)(e1 & 0x3FFFF) * 8 + s];
        uint4 g2 = xin[(size_t)(e2 & 0x3FFFF) * 8 + s];
        uint4 g3 = xin[(size_t)(e3 & 0x3FFFF) * 8 + s];
        PROC(e0, g0); PROC(e1, g1); PROC(e2, g2); PROC(e3, g3);
    }
    for (; i < end; ++i) {
        unsigned e = ed[i];
        uint4 gg = xin[(size_t)(e & 0x3FFFF) * 8 + s];
        PROC(e, gg);
    }
#undef PROC

    if (!last) {
#define EPI(K, AK0, AK1) do { \
        int r = g * 4 + (K); \
        if (r < NTOT) { \
            uint4 o; \
            o.x = (unsigned)benc(AK0.x) | ((unsigned)benc(AK0.y) << 16); \
            o.y = (unsigned)benc(AK0.z) | ((unsigned)benc(AK0.w) << 16); \
            o.z = (unsigned)benc(AK1.x) | ((unsigned)benc(AK1.y) << 16); \
            o.w = (unsigned)benc(AK1.z) | ((unsigned)benc(AK1.w) << 16); \
            yout[(size_t)r * 8 + s] = o; \
        } \
    } while (0)
        EPI(0, A00, A01); EPI(1, A10, A11); EPI(2, A20, A21); EPI(3, A30, A31);
#undef EPI
    } else {
#define EPI(K, AK0, AK1) do { \
        int r = g * 4 + (K); \
        if (r < NTOT) { \
            size_t f4 = (size_t)r * 16 + 2 * s; \
            float4 x0a = (r < NUSERS) ? user[f4]     : item[f4     - (size_t)NUSERS * 16]; \
            float4 x0b = (r < NUSERS) ? user[f4 + 1] : item[f4 + 1 - (size_t)NUSERS * 16]; \
            uint4 u1 = y1[(size_t)r * 8 + s]; \
            uint4 u2 = xin[(size_t)r * 8 + s]; \
            float4 oa, ob; \
            oa.x = 0.25f * (x0a.x + blo(u1.x) + blo(u2.x) + AK0.x); \
            oa.y = 0.25f * (x0a.y + bhi(u1.x) + bhi(u2.x) + AK0.y); \
            oa.z = 0.25f * (x0a.z + blo(u1.y) + blo(u2.y) + AK0.z); \
            oa.w = 0.25f * (x0a.w + bhi(u1.y) + bhi(u2.y) + AK0.w); \
            ob.x = 0.25f * (x0b.x + blo(u1.z) + blo(u2.z) + AK1.x); \
            ob.y = 0.25f * (x0b.y + bhi(u1.z) + bhi(u2.z) + AK1.y); \
            ob.z = 0.25f * (x0b.z + blo(u1.w) + blo(u2.w) + AK1.z); \
            ob.w = 0.25f * (x0b.w + bhi(u1.w) + bhi(u2.w) + AK1.w); \
            out[f4]     = oa; \
            out[f4 + 1] = ob; \
        } \
    } while (0)
        EPI(0, A00, A01); EPI(1, A10, A11); EPI(2, A20, A21); EPI(3, A30, A31);
#undef EPI
    }
}

extern "C" void kernel_launch(void* const* d_in, const int* in_sizes, int n_in,
                              void* d_out, int out_size, void* d_ws, size_t ws_size,
                              hipStream_t stream) {
    const float* user = (const float*)d_in[0];
    const float* item = (const float*)d_in[1];
    const float* vals = (const float*)d_in[2];
    const int*   rows = (const int*)d_in[3];
    const int*   cols = (const int*)d_in[4];
    float* out = (float*)d_out;

    // ws layout (~101 MB): tmp 38.4M | fin 19.2M | bufA 19.2M | bufB 19.2M |
    // cntmat 1.37M | runoffT 1.38M | segoff 1.37M | optr 150K | colTotal | bptr
    char* w = (char*)d_ws;
    int2*     tmp      = (int2*)w;     w += (size_t)NNZ_E * 8;
    unsigned* fin      = (unsigned*)w; w += (size_t)NNZ_E * 4;
    unsigned* bufA     = (unsigned*)w; w += (size_t)NTOT * DIM * 2;   // x0h, later y2h
    unsigned* bufB     = (unsigned*)w; w += (size_t)NTOT * DIM * 2;   // y1h
    int*      cntmat   = (int*)w;      w += (size_t)NPART * NBUCK * 4;
    int*      runoffT  = (int*)w;      w += (size_t)NBUCK * (NPART + 1) * 4;
    int*      segoff   = (int*)w;      w += (size_t)NPART * NBUCK * 4;
    int*      optr     = (int*)w;      w += (size_t)(NOCT + 1) * 4;
    int*      colTotal = (int*)w;      w += (size_t)NBUCK * 4;
    int*      bptr     = (int*)w;

    const int blk = 256;
    const int gConv = (NTOT * 32 + blk - 1) / blk;       // 18750
    const int gSpmm = NOCT / 32;                         // 1172 (4 waves, 8 octs/wave)

    partA1_kernel<<<NPART, 512, 0, stream>>>(rows, cntmat);
    colscan1_kernel<<<NBUCK, 1024, 0, stream>>>(cntmat, runoffT, colTotal);
    colscan2_kernel<<<1, 1024, 0, stream>>>(colTotal, bptr);
    partA2_kernel<<<NPART, 512, 0, stream>>>(rows, cols, vals, cntmat, segoff, tmp);
    partBF_kernel<<<NBUCK, 1024, 0, stream>>>(bptr, runoffT, segoff, tmp, fin, optr);

    convert_kernel<<<gConv, blk, 0, stream>>>((const float2*)user, (const float2*)item, bufA);

    spmm4_kernel<<<gSpmm, blk, 0, stream>>>(optr, fin, (const uint4*)bufA, (uint4*)bufB,
                                            (const float4*)user, (const float4*)item,
                                            (const uint4*)bufB, (float4*)out, 0); // y1=bufB
    spmm4_kernel<<<gSpmm, blk, 0, stream>>>(optr, fin, (const uint4*)bufB, (uint4*)bufA,
                                            (const float4*)user, (const float4*)item,
                                            (const uint4*)bufB, (float4*)out, 0); // y2=bufA
    spmm4_kernel<<<gSpmm, blk, 0, stream>>>(optr, fin, (const uint4*)bufA, (uint4*)bufA,
                                            (const float4*)user, (const float4*)item,
                                            (const uint4*)bufB, (float4*)out, 1); // fused mean
}